// Round 1
// baseline (546.722 us; speedup 1.0000x reference)
//
#include <hip/hip_runtime.h>
#include <stdint.h>

#define BB 2
#define SS 2048
#define DMODEL 512
#define NH 8
#define DHD 64

typedef __attribute__((ext_vector_type(8))) short bf16x8;
typedef __attribute__((ext_vector_type(4))) short s16x4;
typedef __attribute__((ext_vector_type(4))) float fx4;

__device__ __forceinline__ short f2bf(float f) {
    union { float f; uint32_t u; } c; c.f = f;
    uint32_t u = c.u;
    u += 0x7fffu + ((u >> 16) & 1u);   // RNE
    return (short)(u >> 16);
}
__device__ __forceinline__ float bf2f(short s) {
    union { uint32_t u; float f; } c; c.u = ((uint32_t)(uint16_t)s) << 16;
    return c.f;
}

// ---------------------------------------------------------------------------
// C = A(4096x512) @ W(512x512) + bias.  A fp32 or bf16; C fp32 or bf16.
// 64x64 tile, 4 waves, each wave a 32x32 quadrant via 2x2 MFMA 16x16x32 bf16.
// ---------------------------------------------------------------------------
template<int A_BF16, int OUT_BF16>
__global__ __launch_bounds__(256, 4) void gemm_bias_k(
    const void* __restrict__ Ap, const float* __restrict__ W,
    const float* __restrict__ bias, void* __restrict__ Cp)
{
    __shared__ short As[64 * 40];   // [m][k] k-contig, pad 40
    __shared__ short Bs[64 * 40];   // [n][k] (W transposed), pad 40
    const int tid = threadIdx.x;
    const int w = tid >> 6, lane = tid & 63;
    const int cl = lane & 15, quad = lane >> 4;
    const int mi = w >> 1, ni = w & 1;
    const int m0 = blockIdx.x * 64, n0 = blockIdx.y * 64;
    const float* Af = (const float*)Ap;
    const short* Ab = (const short*)Ap;
    fx4 acc[2][2] = {};

    for (int k0 = 0; k0 < DMODEL; k0 += 32) {
        // stage A tile 64x32
#pragma unroll
        for (int it = 0; it < 2; ++it) {
            int idx = tid + it * 256;
            int row = idx >> 3, kq = (idx & 7) * 4;
            s16x4 sv;
            if (A_BF16) {
                sv = *(const s16x4*)&Ab[(size_t)(m0 + row) * DMODEL + k0 + kq];
            } else {
                const float4 vv = *(const float4*)&Af[(size_t)(m0 + row) * DMODEL + k0 + kq];
                sv.x = f2bf(vv.x); sv.y = f2bf(vv.y); sv.z = f2bf(vv.z); sv.w = f2bf(vv.w);
            }
            *(s16x4*)&As[row * 40 + kq] = sv;
        }
        // stage W tile 32x64 transposed -> Bs[n][k]
#pragma unroll
        for (int it = 0; it < 2; ++it) {
            int idx = tid + it * 256;
            int kk = idx >> 4, nq = (idx & 15) * 4;
            const float4 vv = *(const float4*)&W[(size_t)(k0 + kk) * DMODEL + n0 + nq];
            Bs[(nq + 0) * 40 + kk] = f2bf(vv.x);
            Bs[(nq + 1) * 40 + kk] = f2bf(vv.y);
            Bs[(nq + 2) * 40 + kk] = f2bf(vv.z);
            Bs[(nq + 3) * 40 + kk] = f2bf(vv.w);
        }
        __syncthreads();
        bf16x8 af[2], bfr[2];
#pragma unroll
        for (int i = 0; i < 2; ++i)
            af[i] = *(const bf16x8*)&As[(mi * 32 + i * 16 + cl) * 40 + quad * 8];
#pragma unroll
        for (int j = 0; j < 2; ++j)
            bfr[j] = *(const bf16x8*)&Bs[(ni * 32 + j * 16 + cl) * 40 + quad * 8];
#pragma unroll
        for (int i = 0; i < 2; ++i)
#pragma unroll
            for (int j = 0; j < 2; ++j)
                acc[i][j] = __builtin_amdgcn_mfma_f32_16x16x32_bf16(af[i], bfr[j], acc[i][j], 0, 0, 0);
        __syncthreads();
    }
    // epilogue: C/D layout col=lane&15, row=quad*4+reg
#pragma unroll
    for (int i = 0; i < 2; ++i) {
#pragma unroll
        for (int j = 0; j < 2; ++j) {
            int col = n0 + ni * 32 + j * 16 + cl;
            float bv = bias[col];
#pragma unroll
            for (int r = 0; r < 4; ++r) {
                int row = m0 + mi * 32 + i * 16 + quad * 4 + r;
                float v = acc[i][j][r] + bv;
                if (OUT_BF16) ((short*)Cp)[(size_t)row * DMODEL + col] = f2bf(v);
                else          ((float*)Cp)[(size_t)row * DMODEL + col] = v;
            }
        }
    }
}

// ---------------------------------------------------------------------------
// a/b head projections: a[b,h,s] = qp[b,s,:] @ Wa[:,h] + ba[h]   (Wa: 512x8)
// one wave per (b,s) row
// ---------------------------------------------------------------------------
__global__ __launch_bounds__(64) void ab_k(
    const short* __restrict__ qp,
    const float* __restrict__ Wa, const float* __restrict__ ba,
    const float* __restrict__ Wb, const float* __restrict__ bbias,
    float* __restrict__ a_ws, float* __restrict__ b_ws)
{
    const int r = blockIdx.x;
    const int b = r >> 11, s = r & 2047;
    const int lane = threadIdx.x;
    float qv[8];
    s16x4 q0 = *(const s16x4*)&qp[(size_t)r * DMODEL + lane * 8];
    s16x4 q1 = *(const s16x4*)&qp[(size_t)r * DMODEL + lane * 8 + 4];
    qv[0] = bf2f(q0.x); qv[1] = bf2f(q0.y); qv[2] = bf2f(q0.z); qv[3] = bf2f(q0.w);
    qv[4] = bf2f(q1.x); qv[5] = bf2f(q1.y); qv[6] = bf2f(q1.z); qv[7] = bf2f(q1.w);
    float pa[8] = {}, pb[8] = {};
#pragma unroll
    for (int kk = 0; kk < 8; ++kk) {
        int k = lane * 8 + kk;
        const float4 wa0 = *(const float4*)&Wa[k * 8];
        const float4 wa1 = *(const float4*)&Wa[k * 8 + 4];
        const float4 wb0 = *(const float4*)&Wb[k * 8];
        const float4 wb1 = *(const float4*)&Wb[k * 8 + 4];
        float qk = qv[kk];
        pa[0] += qk * wa0.x; pa[1] += qk * wa0.y; pa[2] += qk * wa0.z; pa[3] += qk * wa0.w;
        pa[4] += qk * wa1.x; pa[5] += qk * wa1.y; pa[6] += qk * wa1.z; pa[7] += qk * wa1.w;
        pb[0] += qk * wb0.x; pb[1] += qk * wb0.y; pb[2] += qk * wb0.z; pb[3] += qk * wb0.w;
        pb[4] += qk * wb1.x; pb[5] += qk * wb1.y; pb[6] += qk * wb1.z; pb[7] += qk * wb1.w;
    }
#pragma unroll
    for (int h = 0; h < 8; ++h) {
#pragma unroll
        for (int off = 1; off < 64; off <<= 1) {
            pa[h] += __shfl_xor(pa[h], off);
            pb[h] += __shfl_xor(pb[h], off);
        }
    }
    if (lane == 0) {
#pragma unroll
        for (int h = 0; h < 8; ++h) {
            a_ws[(b * NH + h) * SS + s] = pa[h] + ba[h];
            b_ws[(b * NH + h) * SS + s] = pb[h] + bbias[h];
        }
    }
}

// ---------------------------------------------------------------------------
// Attention: one block per (b,h, 16-row q tile). 4 waves; wave w owns keys
// [w*512, (w+1)*512) with wave-private LDS staging. Scores in regs (128/lane).
// ---------------------------------------------------------------------------
__global__ __launch_bounds__(256, 2) void attn_k(
    const short* __restrict__ qp, const short* __restrict__ kp, const short* __restrict__ vp,
    const float* __restrict__ a_ws, const float* __restrict__ b_ws,
    const float* __restrict__ xdiff, const int* __restrict__ mask,
    float* __restrict__ attn, short* __restrict__ ao)
{
    __shared__ short qs[16 * 72];        // q A-frag layout [i][k]
    __shared__ short kv[4][64 * 72];     // per-wave K ([j][k]) then V^T ([d][j]); aliased as f32 out-reduce
    __shared__ short ps[4][16 * 72];     // per-wave P A-frag staging [i][jlocal]
    __shared__ float redm[64], reds[64], rowa[16], rowb[16];

    const int tid = threadIdx.x;
    const int w = tid >> 6, lane = tid & 63;
    const int cl = lane & 15, quad = lane >> 4;
    const int bh = blockIdx.x;
    const int b = bh >> 3, h = bh & 7;
    const int q0 = blockIdx.y * 16;
    const int bS = b * SS;

    for (int idx = tid; idx < 16 * 64; idx += 256) {
        int i = idx >> 6, k = idx & 63;
        qs[i * 72 + k] = qp[(size_t)(bS + q0 + i) * DMODEL + h * DHD + k];
    }
    if (tid < 16) {
        rowa[tid] = a_ws[(b * NH + h) * SS + q0 + tid];
        rowb[tid] = b_ws[(b * NH + h) * SS + q0 + tid];
    }
    __syncthreads();

    bf16x8 qf[2];
#pragma unroll
    for (int kc = 0; kc < 2; ++kc)
        qf[kc] = *(const bf16x8*)&qs[cl * 72 + kc * 32 + quad * 8];
    float ra[4], rb[4];
#pragma unroll
    for (int r = 0; r < 4; ++r) { ra[r] = rowa[quad * 4 + r]; rb[r] = rowb[quad * 4 + r]; }

    short* kvw = kv[w];
    short* psw = ps[w];
    const int j0w = w * 512;

    fx4 s[8][4];
    float rmax[4] = {-3e38f, -3e38f, -3e38f, -3e38f};

    // ---- QK^T + metric terms, keep scores in regs ----
#pragma unroll
    for (int t = 0; t < 8; ++t) {
        const int j0 = j0w + t * 64;
        // stage K tile (64 keys x 64 dh), rows=keys, k contiguous (B-operand layout)
#pragma unroll
        for (int p = 0; p < 16; ++p) {
            int jr = quad + p * 4;
            *(s16x4*)&kvw[jr * 72 + cl * 4] =
                *(const s16x4*)&kp[(size_t)(bS + j0 + jr) * DMODEL + h * DHD + cl * 4];
        }
        fx4 qk[4] = {};
#pragma unroll
        for (int nb = 0; nb < 4; ++nb)
#pragma unroll
            for (int kc = 0; kc < 2; ++kc) {
                bf16x8 kf = *(const bf16x8*)&kvw[(nb * 16 + cl) * 72 + kc * 32 + quad * 8];
                qk[nb] = __builtin_amdgcn_mfma_f32_16x16x32_bf16(qf[kc], kf, qk[nb], 0, 0, 0);
            }
#pragma unroll
        for (int nb = 0; nb < 4; ++nb) {
            const int j = j0 + nb * 16 + cl;
            const float mv = -1.0e9f * (float)mask[bS + j];
#pragma unroll
            for (int r = 0; r < 4; ++r) {
                const int qi = q0 + quad * 4 + r;
                const float xd = xdiff[(size_t)(bS + qi) * SS + j];
                float v = qk[nb][r] * 0.125f + mv + ra[r] * xd + rb[r] * (xd * xd);
                s[t][nb][r] = v;
                rmax[r] = fmaxf(rmax[r], v);
            }
        }
    }

    // ---- row max (16 lanes per row, then cross-wave via LDS) ----
#pragma unroll
    for (int off = 1; off < 16; off <<= 1)
#pragma unroll
        for (int r = 0; r < 4; ++r)
            rmax[r] = fmaxf(rmax[r], __shfl_xor(rmax[r], off));
    if (cl == 0)
#pragma unroll
        for (int r = 0; r < 4; ++r) redm[w * 16 + quad * 4 + r] = rmax[r];
    __syncthreads();
    float gm[4];
#pragma unroll
    for (int r = 0; r < 4; ++r) {
        int i = quad * 4 + r;
        gm[r] = fmaxf(fmaxf(redm[i], redm[16 + i]), fmaxf(redm[32 + i], redm[48 + i]));
    }

    // ---- exp + row sum ----
    float rsum[4] = {};
#pragma unroll
    for (int t = 0; t < 8; ++t)
#pragma unroll
        for (int nb = 0; nb < 4; ++nb)
#pragma unroll
            for (int r = 0; r < 4; ++r) {
                float e = exp2f((s[t][nb][r] - gm[r]) * 1.44269504f);
                s[t][nb][r] = e;
                rsum[r] += e;
            }
#pragma unroll
    for (int off = 1; off < 16; off <<= 1)
#pragma unroll
        for (int r = 0; r < 4; ++r)
            rsum[r] += __shfl_xor(rsum[r], off);
    if (cl == 0)
#pragma unroll
        for (int r = 0; r < 4; ++r) reds[w * 16 + quad * 4 + r] = rsum[r];
    __syncthreads();
    float gs[4];
#pragma unroll
    for (int r = 0; r < 4; ++r) {
        int i = quad * 4 + r;
        gs[r] = 1.0f / (reds[i] + reds[16 + i] + reds[32 + i] + reds[48 + i]);
    }

    // ---- normalize, write attn, PV ----
    fx4 oacc[4] = {};
    float* attn_bh = attn + (size_t)(b * NH + h) * SS * SS;
#pragma unroll
    for (int t = 0; t < 8; ++t) {
        const int j0 = j0w + t * 64;
        // stage V^T tile: kvw[d][j], d rows (64), j contiguous (B-operand for PV)
#pragma unroll
        for (int p4 = 0; p4 < 16; ++p4) {
            s16x4 tmp;
            tmp.x = vp[(size_t)(bS + j0 + p4 * 4 + 0) * DMODEL + h * DHD + lane];
            tmp.y = vp[(size_t)(bS + j0 + p4 * 4 + 1) * DMODEL + h * DHD + lane];
            tmp.z = vp[(size_t)(bS + j0 + p4 * 4 + 2) * DMODEL + h * DHD + lane];
            tmp.w = vp[(size_t)(bS + j0 + p4 * 4 + 3) * DMODEL + h * DHD + lane];
            *(s16x4*)&kvw[lane * 72 + p4 * 4] = tmp;
        }
        // normalize + write attn (fp32) + stage P (bf16, A-frag layout)
#pragma unroll
        for (int nb = 0; nb < 4; ++nb) {
            const int j = j0 + nb * 16 + cl;
#pragma unroll
            for (int r = 0; r < 4; ++r) {
                float p = s[t][nb][r] * gs[r];
                attn_bh[(size_t)(q0 + quad * 4 + r) * SS + j] = p;
                psw[(quad * 4 + r) * 72 + nb * 16 + cl] = f2bf(p);
            }
        }
        bf16x8 pf[2];
#pragma unroll
        for (int kc = 0; kc < 2; ++kc)
            pf[kc] = *(const bf16x8*)&psw[cl * 72 + kc * 32 + quad * 8];
#pragma unroll
        for (int nb = 0; nb < 4; ++nb)
#pragma unroll
            for (int kc = 0; kc < 2; ++kc) {
                bf16x8 vf = *(const bf16x8*)&kvw[(nb * 16 + cl) * 72 + kc * 32 + quad * 8];
                oacc[nb] = __builtin_amdgcn_mfma_f32_16x16x32_bf16(pf[kc], vf, oacc[nb], 0, 0, 0);
            }
    }

    // ---- cross-wave output reduction (alias kv as fp32 scratch) ----
    __syncthreads();
    float* ored = (float*)kv;   // 4*16*64 floats = 16 KB
#pragma unroll
    for (int nb = 0; nb < 4; ++nb)
#pragma unroll
        for (int r = 0; r < 4; ++r)
            ored[w * 1024 + (quad * 4 + r) * 64 + nb * 16 + cl] = oacc[nb][r];
    __syncthreads();
    {
        int i = tid >> 4, dq = (tid & 15) * 4;
        float sx = 0, sy = 0, sz = 0, sw = 0;
#pragma unroll
        for (int ww = 0; ww < 4; ++ww) {
            const float4 vv = *(const float4*)&ored[ww * 1024 + i * 64 + dq];
            sx += vv.x; sy += vv.y; sz += vv.z; sw += vv.w;
        }
        s16x4 o;
        o.x = f2bf(sx); o.y = f2bf(sy); o.z = f2bf(sz); o.w = f2bf(sw);
        *(s16x4*)&ao[(size_t)(bS + q0 + i) * DMODEL + h * DHD + dq] = o;
    }
}

// ---------------------------------------------------------------------------
extern "C" void kernel_launch(void* const* d_in, const int* in_sizes, int n_in,
                              void* d_out, int out_size, void* d_ws, size_t ws_size,
                              hipStream_t stream)
{
    (void)in_sizes; (void)n_in; (void)out_size; (void)ws_size;
    const float* q     = (const float*)d_in[0];
    const float* k     = (const float*)d_in[1];
    const float* v     = (const float*)d_in[2];
    const float* xdiff = (const float*)d_in[3];
    const int*   mask  = (const int*)d_in[4];
    const float* Wq = (const float*)d_in[5];
    const float* bq = (const float*)d_in[6];
    const float* Wk = (const float*)d_in[7];
    const float* bk = (const float*)d_in[8];
    const float* Wv = (const float*)d_in[9];
    const float* bv = (const float*)d_in[10];
    const float* Wa = (const float*)d_in[11];
    const float* ba = (const float*)d_in[12];
    const float* Wb = (const float*)d_in[13];
    const float* bb = (const float*)d_in[14];
    const float* Wo = (const float*)d_in[15];
    const float* bo = (const float*)d_in[16];

    char* ws = (char*)d_ws;
    short* qp   = (short*)(ws + 0);          // 4096x512 bf16
    short* kp   = (short*)(ws + 4194304);
    short* vp   = (short*)(ws + 8388608);
    float* a_ws = (float*)(ws + 12582912);   // (B,H,S) f32
    float* b_ws = (float*)(ws + 12713984);
    short* ao   = (short*)(ws + 12845056);   // 4096x512 bf16 (attn output pre-Wo)

    float* out  = (float*)d_out;
    float* attn = out + (size_t)BB * SS * DMODEL;

    dim3 g(64, 8), blk(256);
    hipLaunchKernelGGL((gemm_bias_k<0, 1>), g, blk, 0, stream, q, Wq, bq, qp);
    hipLaunchKernelGGL((gemm_bias_k<0, 1>), g, blk, 0, stream, k, Wk, bk, kp);
    hipLaunchKernelGGL((gemm_bias_k<0, 1>), g, blk, 0, stream, v, Wv, bv, vp);
    hipLaunchKernelGGL(ab_k, dim3(4096), dim3(64), 0, stream, qp, Wa, ba, Wb, bb, a_ws, b_ws);
    hipLaunchKernelGGL(attn_k, dim3(16, 128), dim3(256), 0, stream,
                       qp, kp, vp, a_ws, b_ws, xdiff, mask, attn, ao);
    hipLaunchKernelGGL((gemm_bias_k<1, 0>), g, blk, 0, stream, ao, Wo, bo, out);
}